// Round 6
// baseline (1797.486 us; speedup 1.0000x reference)
//
#include <hip/hip_runtime.h>

typedef _Float16 half8 __attribute__((ext_vector_type(8)));
typedef float floatx4 __attribute__((ext_vector_type(4)));

#define T_STEPS 20
#define NSEQ 131072
#define HID 192
#define ROWS 32
#define HPAD 200            // fp16 elems per LDS h-row (400 B stride; bank step 4 -> 2-way, free)
#define REGA_SZ 49152       // kc 0..1 frags  [12ht][2kc][4g][64][8]  -> LDS
#define REGB_SZ 98304       // kc 2..5 frags  [12ht][4kc2][4g][64][8] -> registers
#define REGW_OFF (REGA_SZ + REGB_SZ)   // wout frags [6kc][64][8]

__device__ __forceinline__ float fsig(float x) {
    return __builtin_amdgcn_rcpf(1.f + __builtin_amdgcn_exp2f(-1.4426950408889634f * x));
}
__device__ __forceinline__ float ftanh(float x) {
    return 1.f - 2.f * __builtin_amdgcn_rcpf(__builtin_amdgcn_exp2f(2.8853900817779268f * x) + 1.f);
}

// Rewrite w_hh / w_out into MFMA B-fragment order (fp16).
// B-frag 16x16x32: lane L = q*16 + n holds k = q*8..q*8+7 of column n.
__global__ void build_frags(const float* __restrict__ whh,
                            const float* __restrict__ wout,
                            _Float16* __restrict__ dst) {
    int i = blockIdx.x * 256 + threadIdx.x;
    if (i < REGA_SZ) {
        int e = i & 7, L = (i >> 3) & 63, g = (i >> 9) & 3, kc = (i >> 11) & 1, ht = i >> 12;
        int n = L & 15, q = L >> 4;
        dst[i] = (_Float16)whh[(size_t)(g * HID + ht * 16 + n) * HID + kc * 32 + q * 8 + e];
    } else if (i < REGW_OFF) {
        int j = i - REGA_SZ;
        int e = j & 7, L = (j >> 3) & 63, g = (j >> 9) & 3, kc2 = (j >> 11) & 3, ht = j >> 13;
        int n = L & 15, q = L >> 4;
        dst[i] = (_Float16)whh[(size_t)(g * HID + ht * 16 + n) * HID + (kc2 + 2) * 32 + q * 8 + e];
    } else if (i < REGW_OFF + 3072) {
        int k = i - REGW_OFF;
        int e = k & 7, L = (k >> 3) & 63, kc = k >> 9;
        int n = L & 15, q = L >> 4;
        dst[i] = (_Float16)((n < 2) ? wout[n * HID + kc * 32 + q * 8 + e] : 0.f);
    }
}

// 768 threads = 12 waves = exactly 3 waves/SIMD (1 block/CU, LDS-capped at 135 KB).
// Raw attributes (not __launch_bounds__): flat_work_group_size pins WG=768 and
// waves_per_eu(3,3) pins the allocator budget at 512/3 = 170 regs/wave.
__global__ __attribute__((amdgpu_flat_work_group_size(768, 768), amdgpu_waves_per_eu(3, 3)))
void lstm_fused_kernel(
    const float* __restrict__ obs,       // [20][N][2]
    const float* __restrict__ h0,        // [N][192]
    const float* __restrict__ w_ih,      // [768][2]
    const float* __restrict__ b_ih,      // [768]
    const float* __restrict__ b_hh,      // [768]
    const float* __restrict__ b_out,     // [2]
    const _Float16* __restrict__ frags,  // whh + wout fragments (fp16)
    float* __restrict__ out)             // [20][N][2]
{
    __shared__ _Float16 b_lds[REGA_SZ];          // 98304 B: whh kc 0..1
    __shared__ _Float16 hbuf[2][ROWS][HPAD];     // 25600 B: h double-buffered
    __shared__ _Float16 wo_lds[3072];            //  6144 B: wout frags
    __shared__ float2 x_all[T_STEPS][ROWS];      //  5120 B: all steps' x

    const int tid  = threadIdx.x;
    const int wave = tid >> 6;       // 0..11 = hidden-col tile
    const int lane = tid & 63;
    const int quad = lane >> 4;
    const int l16  = lane & 15;
    const int ht   = wave;
    const int base = blockIdx.x * ROWS;

    // ---- one-time staging ----
    for (int i = tid; i < REGA_SZ / 8; i += 768)
        *(half8*)&b_lds[i * 8] = *(const half8*)&frags[i * 8];
    if (tid < 384)
        *(half8*)&wo_lds[tid * 8] = *(const half8*)&frags[REGW_OFF + tid * 8];
    for (int i = tid; i < ROWS * HID / 4; i += 768) {
        float4 v = *(const float4*)&h0[(size_t)base * HID + i * 4];
        int row = (i * 4) / HID, k = (i * 4) - row * HID;
        hbuf[0][row][k]     = (_Float16)v.x;
        hbuf[0][row][k + 1] = (_Float16)v.y;
        hbuf[0][row][k + 2] = (_Float16)v.z;
        hbuf[0][row][k + 3] = (_Float16)v.w;
    }
    if (tid < T_STEPS * ROWS) {      // x for all steps, once
        int t = tid >> 5, r = tid & 31;
        int src = (t == 0) ? 0 : (t - 1);
        x_all[t][r] = *(const float2*)&obs[((size_t)src * NSEQ + base + r) * 2];
    }

    // ---- per-wave register-resident B fragments (kc 2..5): 64 VGPRs ----
    half8 breg[16];
    {
        const _Float16* p = frags + REGA_SZ + ht * 8192 + lane * 8;
#pragma unroll
        for (int q = 0; q < 16; ++q)
            breg[q] = *(const half8*)(p + q * 512);
    }
    const float bo_n = (l16 < 2) ? b_out[l16] : 0.f;

    float c[8];
#pragma unroll
    for (int i = 0; i < 8; ++i) c[i] = 0.f;

    const int j = ht * 16 + l16;
    float bs[4], w0[4], w1[4];
#pragma unroll
    for (int g = 0; g < 4; ++g) {
        bs[g] = b_ih[g * HID + j] + b_hh[g * HID + j];
        w0[g] = w_ih[(g * HID + j) * 2];
        w1[g] = w_ih[(g * HID + j) * 2 + 1];
    }

    __syncthreads();

    for (int t = 0; t < T_STEPS; ++t) {
        const _Float16* hb = &hbuf[t & 1][0][0];
        _Float16*       hn = &hbuf[(t + 1) & 1][0][0];

        // ================= gate MFMA phase (reads hbuf[t&1]) =================
        floatx4 acc[2][4];
#pragma unroll
        for (int rt = 0; rt < 2; ++rt)
#pragma unroll
            for (int g = 0; g < 4; ++g)
                acc[rt][g] = (floatx4){0.f, 0.f, 0.f, 0.f};

#pragma unroll
        for (int kc = 0; kc < 2; ++kc) {
            half8 bt[4];
#pragma unroll
            for (int g = 0; g < 4; ++g)
                bt[g] = *(const half8*)&b_lds[((ht * 2 + kc) * 4 + g) * 512 + lane * 8];
#pragma unroll
            for (int rt = 0; rt < 2; ++rt) {
                half8 a = *(const half8*)(hb + (rt * 16 + l16) * HPAD + kc * 32 + quad * 8);
#pragma unroll
                for (int g = 0; g < 4; ++g)
                    acc[rt][g] = __builtin_amdgcn_mfma_f32_16x16x32_f16(a, bt[g], acc[rt][g], 0, 0, 0);
            }
        }
#pragma unroll
        for (int kc2 = 0; kc2 < 4; ++kc2) {
#pragma unroll
            for (int rt = 0; rt < 2; ++rt) {
                half8 a = *(const half8*)(hb + (rt * 16 + l16) * HPAD + (kc2 + 2) * 32 + quad * 8);
#pragma unroll
                for (int g = 0; g < 4; ++g)
                    acc[rt][g] = __builtin_amdgcn_mfma_f32_16x16x32_f16(a, breg[kc2 * 4 + g], acc[rt][g], 0, 0, 0);
            }
        }

        // ---- out_{t-1} = h_t @ w_out.T + b_out (wave 0, also reads hbuf[t&1]) ----
        if (ht == 0 && t > 0) {
            const int ot = t - 1;
#pragma unroll
            for (int rt = 0; rt < 2; ++rt) {
                floatx4 ao = {bo_n, bo_n, bo_n, bo_n};
#pragma unroll
                for (int kc = 0; kc < 6; ++kc) {
                    half8 a = *(const half8*)(hb + (rt * 16 + l16) * HPAD + kc * 32 + quad * 8);
                    half8 b = *(const half8*)&wo_lds[kc * 512 + lane * 8];
                    ao = __builtin_amdgcn_mfma_f32_16x16x32_f16(a, b, ao, 0, 0, 0);
                }
                if (l16 < 2) {
#pragma unroll
                    for (int r = 0; r < 4; ++r)
                        out[((size_t)ot * NSEQ + base + rt * 16 + quad * 4 + r) * 2 + l16] = ao[r];
                }
            }
        }

        // ============ activation phase (writes hbuf[(t+1)&1]) ============
        // sched_barrier(0) after each unit: caps live transcendental temps to
        // ONE unit's worth, keeping peak pressure under the 170-reg budget so
        // breg is never the spill victim.
#pragma unroll
        for (int rt = 0; rt < 2; ++rt) {
#pragma unroll
            for (int r = 0; r < 4; ++r) {
                const int row = rt * 16 + quad * 4 + r;
                const float2 xv = x_all[t][row];
                const float gi = acc[rt][0][r] + bs[0] + xv.x * w0[0] + xv.y * w1[0];
                const float gf = acc[rt][1][r] + bs[1] + xv.x * w0[1] + xv.y * w1[1];
                const float gg = acc[rt][2][r] + bs[2] + xv.x * w0[2] + xv.y * w1[2];
                const float go = acc[rt][3][r] + bs[3] + xv.x * w0[3] + xv.y * w1[3];
                const int ci = rt * 4 + r;
                const float cn = fsig(gf) * c[ci] + fsig(gi) * ftanh(gg);
                c[ci] = cn;
                hn[row * HPAD + j] = (_Float16)(fsig(go) * ftanh(cn));
                __builtin_amdgcn_sched_barrier(0);
            }
        }
        __syncthreads();   // h_{t+1} done; all hbuf[t&1] reads done -> next step safe
    }

    // ---- out_19 from h_20 (in hbuf[0]) ----
    if (ht == 0) {
        const _Float16* hb = &hbuf[0][0][0];
#pragma unroll
        for (int rt = 0; rt < 2; ++rt) {
            floatx4 ao = {bo_n, bo_n, bo_n, bo_n};
#pragma unroll
            for (int kc = 0; kc < 6; ++kc) {
                half8 a = *(const half8*)(hb + (rt * 16 + l16) * HPAD + kc * 32 + quad * 8);
                half8 b = *(const half8*)&wo_lds[kc * 512 + lane * 8];
                ao = __builtin_amdgcn_mfma_f32_16x16x32_f16(a, b, ao, 0, 0, 0);
            }
            if (l16 < 2) {
#pragma unroll
                for (int r = 0; r < 4; ++r)
                    out[((size_t)19 * NSEQ + base + rt * 16 + quad * 4 + r) * 2 + l16] = ao[r];
            }
        }
    }
}

extern "C" void kernel_launch(void* const* d_in, const int* in_sizes, int n_in,
                              void* d_out, int out_size, void* d_ws, size_t ws_size,
                              hipStream_t stream) {
    const float* obs  = (const float*)d_in[0];
    const float* h0   = (const float*)d_in[1];
    const float* wih  = (const float*)d_in[2];
    const float* whh  = (const float*)d_in[3];
    const float* bih  = (const float*)d_in[4];
    const float* bhh  = (const float*)d_in[5];
    const float* wout = (const float*)d_in[6];
    const float* bout = (const float*)d_in[7];
    float* out = (float*)d_out;
    _Float16* frags = (_Float16*)d_ws;   // 301056 B used

    build_frags<<<(REGW_OFF + 3072 + 255) / 256, 256, 0, stream>>>(whh, wout, frags);
    lstm_fused_kernel<<<NSEQ / ROWS, 768, 0, stream>>>(
        obs, h0, wih, bih, bhh, bout, frags, out);
}

// Round 7
// 1354.248 us; speedup vs baseline: 1.3273x; 1.3273x over previous
//
#include <hip/hip_runtime.h>

typedef _Float16 half8 __attribute__((ext_vector_type(8)));
typedef float floatx4 __attribute__((ext_vector_type(4)));

#define T_STEPS 20
#define NSEQ 131072
#define HID 192
#define ROWS 32
#define HPAD 200            // fp16 elems per LDS h-row (400 B stride; bank step 4 -> 2-way, free)
#define REGA_SZ 49152       // kc 0..1 frags  [12ht][2kc][4g][64][8]  -> LDS (per block)
#define REGB_SZ 98304       // kc 2..5 frags  [12ht][4kc2][4g][64][8] -> streamed from L2 each step
#define REGW_OFF (REGA_SZ + REGB_SZ)   // wout frags [6kc][64][8]

__device__ __forceinline__ float fsig(float x) {
    return __builtin_amdgcn_rcpf(1.f + __builtin_amdgcn_exp2f(-1.4426950408889634f * x));
}
__device__ __forceinline__ float ftanh(float x) {
    return 1.f - 2.f * __builtin_amdgcn_rcpf(__builtin_amdgcn_exp2f(2.8853900817779268f * x) + 1.f);
}

// Rewrite w_hh / w_out into MFMA B-fragment order (fp16).
// B-frag 16x16x32: lane L = q*16 + n holds k = q*8..q*8+7 of column n.
__global__ void build_frags(const float* __restrict__ whh,
                            const float* __restrict__ wout,
                            _Float16* __restrict__ dst) {
    int i = blockIdx.x * 256 + threadIdx.x;
    if (i < REGA_SZ) {
        int e = i & 7, L = (i >> 3) & 63, g = (i >> 9) & 3, kc = (i >> 11) & 1, ht = i >> 12;
        int n = L & 15, q = L >> 4;
        dst[i] = (_Float16)whh[(size_t)(g * HID + ht * 16 + n) * HID + kc * 32 + q * 8 + e];
    } else if (i < REGW_OFF) {
        int j = i - REGA_SZ;
        int e = j & 7, L = (j >> 3) & 63, g = (j >> 9) & 3, kc2 = (j >> 11) & 3, ht = j >> 13;
        int n = L & 15, q = L >> 4;
        dst[i] = (_Float16)whh[(size_t)(g * HID + ht * 16 + n) * HID + (kc2 + 2) * 32 + q * 8 + e];
    } else if (i < REGW_OFF + 3072) {
        int k = i - REGW_OFF;
        int e = k & 7, L = (k >> 3) & 63, kc = k >> 9;
        int n = L & 15, q = L >> 4;
        dst[i] = (_Float16)((n < 2) ? wout[n * HID + kc * 32 + q * 8 + e] : 0.f);
    }
}

// 768 threads = 12 waves = 3 waves/SIMD (1 block/CU, LDS-capped at 135 KB).
// B-frags for kc 2..5 are STREAMED from the L2-hot frag table every step
// (prefetched at step top, consumed after the LDS-kc MFMAs) so no weight
// registers are live across the activation phase -> no spill.
__global__ __launch_bounds__(768) void lstm_fused_kernel(
    const float* __restrict__ obs,       // [20][N][2]
    const float* __restrict__ h0,        // [N][192]
    const float* __restrict__ w_ih,      // [768][2]
    const float* __restrict__ b_ih,      // [768]
    const float* __restrict__ b_hh,      // [768]
    const float* __restrict__ b_out,     // [2]
    const _Float16* __restrict__ frags,  // whh + wout fragments (fp16)
    float* __restrict__ out)             // [20][N][2]
{
    __shared__ _Float16 b_lds[REGA_SZ];          // 98304 B: whh kc 0..1
    __shared__ _Float16 hbuf[2][ROWS][HPAD];     // 25600 B: h double-buffered
    __shared__ _Float16 wo_lds[3072];            //  6144 B: wout frags
    __shared__ float2 x_all[T_STEPS][ROWS];      //  5120 B: all steps' x

    const int tid  = threadIdx.x;
    const int wave = tid >> 6;       // 0..11 = hidden-col tile
    const int lane = tid & 63;
    const int quad = lane >> 4;
    const int l16  = lane & 15;
    const int ht   = wave;
    const int base = blockIdx.x * ROWS;

    // ---- one-time staging ----
    for (int i = tid; i < REGA_SZ / 8; i += 768)
        *(half8*)&b_lds[i * 8] = *(const half8*)&frags[i * 8];
    if (tid < 384)
        *(half8*)&wo_lds[tid * 8] = *(const half8*)&frags[REGW_OFF + tid * 8];
    for (int i = tid; i < ROWS * HID / 4; i += 768) {
        float4 v = *(const float4*)&h0[(size_t)base * HID + i * 4];
        int row = (i * 4) / HID, k = (i * 4) - row * HID;
        hbuf[0][row][k]     = (_Float16)v.x;
        hbuf[0][row][k + 1] = (_Float16)v.y;
        hbuf[0][row][k + 2] = (_Float16)v.z;
        hbuf[0][row][k + 3] = (_Float16)v.w;
    }
    if (tid < T_STEPS * ROWS) {      // x for all steps, once
        int t = tid >> 5, r = tid & 31;
        int src = (t == 0) ? 0 : (t - 1);
        x_all[t][r] = *(const float2*)&obs[((size_t)src * NSEQ + base + r) * 2];
    }

    const float bo_n = (l16 < 2) ? b_out[l16] : 0.f;

    float c[8];
#pragma unroll
    for (int i = 0; i < 8; ++i) c[i] = 0.f;

    const int j = ht * 16 + l16;
    float bs[4], w0[4], w1[4];
#pragma unroll
    for (int g = 0; g < 4; ++g) {
        bs[g] = b_ih[g * HID + j] + b_hh[g * HID + j];
        w0[g] = w_ih[(g * HID + j) * 2];
        w1[g] = w_ih[(g * HID + j) * 2 + 1];
    }

    __syncthreads();

    for (int t = 0; t < T_STEPS; ++t) {
        const _Float16* hb = &hbuf[t & 1][0][0];
        _Float16*       hn = &hbuf[(t + 1) & 1][0][0];

        // ---- stream this wave's kc 2..5 B-frags (L2-hot, 256 B/lane).
        // Opaque pointer copy defeats LICM/CSE so these are re-issued every
        // step (live range confined to the MFMA phase -> no spill).
        const _Float16* ps = frags + REGA_SZ + ht * 8192 + lane * 8;
        asm volatile("" : "+v"(ps));
        half8 bst[16];
#pragma unroll
        for (int q = 0; q < 16; ++q)
            bst[q] = *(const half8*)(ps + q * 512);

        // ================= gate MFMA phase (reads hbuf[t&1]) =================
        floatx4 acc[2][4];
#pragma unroll
        for (int rt = 0; rt < 2; ++rt)
#pragma unroll
            for (int g = 0; g < 4; ++g)
                acc[rt][g] = (floatx4){0.f, 0.f, 0.f, 0.f};

        // LDS-resident slices kc 0..1 (gives the stream ~220 cyc to land)
#pragma unroll
        for (int kc = 0; kc < 2; ++kc) {
            half8 bt[4];
#pragma unroll
            for (int g = 0; g < 4; ++g)
                bt[g] = *(const half8*)&b_lds[((ht * 2 + kc) * 4 + g) * 512 + lane * 8];
#pragma unroll
            for (int rt = 0; rt < 2; ++rt) {
                half8 a = *(const half8*)(hb + (rt * 16 + l16) * HPAD + kc * 32 + quad * 8);
#pragma unroll
                for (int g = 0; g < 4; ++g)
                    acc[rt][g] = __builtin_amdgcn_mfma_f32_16x16x32_f16(a, bt[g], acc[rt][g], 0, 0, 0);
            }
        }
        // streamed slices kc 2..5
#pragma unroll
        for (int kc2 = 0; kc2 < 4; ++kc2) {
#pragma unroll
            for (int rt = 0; rt < 2; ++rt) {
                half8 a = *(const half8*)(hb + (rt * 16 + l16) * HPAD + (kc2 + 2) * 32 + quad * 8);
#pragma unroll
                for (int g = 0; g < 4; ++g)
                    acc[rt][g] = __builtin_amdgcn_mfma_f32_16x16x32_f16(a, bst[kc2 * 4 + g], acc[rt][g], 0, 0, 0);
            }
        }

        // ---- out_{t-1} = h_t @ w_out.T + b_out (wave 0, also reads hbuf[t&1]) ----
        if (ht == 0 && t > 0) {
            const int ot = t - 1;
#pragma unroll
            for (int rt = 0; rt < 2; ++rt) {
                floatx4 ao = {bo_n, bo_n, bo_n, bo_n};
#pragma unroll
                for (int kc = 0; kc < 6; ++kc) {
                    half8 a = *(const half8*)(hb + (rt * 16 + l16) * HPAD + kc * 32 + quad * 8);
                    half8 b = *(const half8*)&wo_lds[kc * 512 + lane * 8];
                    ao = __builtin_amdgcn_mfma_f32_16x16x32_f16(a, b, ao, 0, 0, 0);
                }
                if (l16 < 2) {
#pragma unroll
                    for (int r = 0; r < 4; ++r)
                        out[((size_t)ot * NSEQ + base + rt * 16 + quad * 4 + r) * 2 + l16] = ao[r];
                }
            }
        }

        // ============ activation phase (writes hbuf[(t+1)&1]) ============
#pragma unroll
        for (int rt = 0; rt < 2; ++rt) {
#pragma unroll
            for (int r = 0; r < 4; ++r) {
                const int row = rt * 16 + quad * 4 + r;
                const float2 xv = x_all[t][row];
                const float gi = acc[rt][0][r] + bs[0] + xv.x * w0[0] + xv.y * w1[0];
                const float gf = acc[rt][1][r] + bs[1] + xv.x * w0[1] + xv.y * w1[1];
                const float gg = acc[rt][2][r] + bs[2] + xv.x * w0[2] + xv.y * w1[2];
                const float go = acc[rt][3][r] + bs[3] + xv.x * w0[3] + xv.y * w1[3];
                const int ci = rt * 4 + r;
                const float cn = fsig(gf) * c[ci] + fsig(gi) * ftanh(gg);
                c[ci] = cn;
                hn[row * HPAD + j] = (_Float16)(fsig(go) * ftanh(cn));
            }
        }
        __syncthreads();   // h_{t+1} done; all hbuf[t&1] reads done -> next step safe
    }

    // ---- out_19 from h_20 (in hbuf[0]) ----
    if (ht == 0) {
        const _Float16* hb = &hbuf[0][0][0];
#pragma unroll
        for (int rt = 0; rt < 2; ++rt) {
            floatx4 ao = {bo_n, bo_n, bo_n, bo_n};
#pragma unroll
            for (int kc = 0; kc < 6; ++kc) {
                half8 a = *(const half8*)(hb + (rt * 16 + l16) * HPAD + kc * 32 + quad * 8);
                half8 b = *(const half8*)&wo_lds[kc * 512 + lane * 8];
                ao = __builtin_amdgcn_mfma_f32_16x16x32_f16(a, b, ao, 0, 0, 0);
            }
            if (l16 < 2) {
#pragma unroll
                for (int r = 0; r < 4; ++r)
                    out[((size_t)19 * NSEQ + base + rt * 16 + quad * 4 + r) * 2 + l16] = ao[r];
            }
        }
    }
}

extern "C" void kernel_launch(void* const* d_in, const int* in_sizes, int n_in,
                              void* d_out, int out_size, void* d_ws, size_t ws_size,
                              hipStream_t stream) {
    const float* obs  = (const float*)d_in[0];
    const float* h0   = (const float*)d_in[1];
    const float* wih  = (const float*)d_in[2];
    const float* whh  = (const float*)d_in[3];
    const float* bih  = (const float*)d_in[4];
    const float* bhh  = (const float*)d_in[5];
    const float* wout = (const float*)d_in[6];
    const float* bout = (const float*)d_in[7];
    float* out = (float*)d_out;
    _Float16* frags = (_Float16*)d_ws;   // 301056 B used

    build_frags<<<(REGW_OFF + 3072 + 255) / 256, 256, 0, stream>>>(whh, wout, frags);
    lstm_fused_kernel<<<NSEQ / ROWS, 768, 0, stream>>>(
        obs, h0, wih, bih, bhh, bout, frags, out);
}

// Round 8
// 1305.391 us; speedup vs baseline: 1.3770x; 1.0374x over previous
//
#include <hip/hip_runtime.h>

typedef _Float16 half8 __attribute__((ext_vector_type(8)));
typedef float floatx4 __attribute__((ext_vector_type(4)));

#define T_STEPS 20
#define NSEQ 131072
#define HID 192
#define ROWS 32
#define HPAD 200            // fp16 elems per LDS h-row (400 B stride)
#define REGA_SZ 49152       // kc 0..1 frags  [12ht][2kc][4g][64][8]  -> LDS (per block)
#define REGB_SZ 98304       // kc 2..5 frags  [12ht][4kc2][4g][64][8] -> streamed from L2
#define REGW_OFF (REGA_SZ + REGB_SZ)   // wout frags [6kc][64][8]

__device__ __forceinline__ float fsig(float x) {
    return __builtin_amdgcn_rcpf(1.f + __builtin_amdgcn_exp2f(-1.4426950408889634f * x));
}
__device__ __forceinline__ float ftanh(float x) {
    return 1.f - 2.f * __builtin_amdgcn_rcpf(__builtin_amdgcn_exp2f(2.8853900817779268f * x) + 1.f);
}

// Rewrite w_hh / w_out into MFMA B-fragment order (fp16).
// B-frag 16x16x32: lane L = q*16 + n holds k = q*8..q*8+7 of column n.
__global__ void build_frags(const float* __restrict__ whh,
                            const float* __restrict__ wout,
                            _Float16* __restrict__ dst) {
    int i = blockIdx.x * 256 + threadIdx.x;
    if (i < REGA_SZ) {
        int e = i & 7, L = (i >> 3) & 63, g = (i >> 9) & 3, kc = (i >> 11) & 1, ht = i >> 12;
        int n = L & 15, q = L >> 4;
        dst[i] = (_Float16)whh[(size_t)(g * HID + ht * 16 + n) * HID + kc * 32 + q * 8 + e];
    } else if (i < REGW_OFF) {
        int j = i - REGA_SZ;
        int e = j & 7, L = (j >> 3) & 63, g = (j >> 9) & 3, kc2 = (j >> 11) & 3, ht = j >> 13;
        int n = L & 15, q = L >> 4;
        dst[i] = (_Float16)whh[(size_t)(g * HID + ht * 16 + n) * HID + (kc2 + 2) * 32 + q * 8 + e];
    } else if (i < REGW_OFF + 3072) {
        int k = i - REGW_OFF;
        int e = k & 7, L = (k >> 3) & 63, kc = k >> 9;
        int n = L & 15, q = L >> 4;
        dst[i] = (_Float16)((n < 2) ? wout[n * HID + kc * 32 + q * 8 + e] : 0.f);
    }
}

// 768 threads = 12 waves = 3 waves/SIMD (1 block/CU, LDS-capped at 135 KB).
// Weight stream split across the barrier: kc2-3 prefetched pre-barrier
// (in flight through barrier drain + next step's LDS MFMAs), kc4-5 at
// step top. No weight regs live through the activation phase.
__global__ __launch_bounds__(768) void lstm_fused_kernel(
    const float* __restrict__ obs,       // [20][N][2]
    const float* __restrict__ h0,        // [N][192]
    const float* __restrict__ w_ih,      // [768][2]
    const float* __restrict__ b_ih,      // [768]
    const float* __restrict__ b_hh,      // [768]
    const float* __restrict__ b_out,     // [2]
    const _Float16* __restrict__ frags,  // whh + wout fragments (fp16)
    float* __restrict__ out)             // [20][N][2]
{
    __shared__ _Float16 b_lds[REGA_SZ];          // 98304 B: whh kc 0..1
    __shared__ _Float16 hbuf[2][ROWS][HPAD];     // 25600 B: h double-buffered
    __shared__ _Float16 wo_lds[3072];            //  6144 B: wout frags
    __shared__ float2 x_all[T_STEPS][ROWS];      //  5120 B: all steps' x

    const int tid  = threadIdx.x;
    const int wave = tid >> 6;       // 0..11 = hidden-col tile
    const int lane = tid & 63;
    const int quad = lane >> 4;
    const int l16  = lane & 15;
    const int ht   = wave;
    const int base = blockIdx.x * ROWS;

    // ---- one-time staging ----
    for (int i = tid; i < REGA_SZ / 8; i += 768)
        *(half8*)&b_lds[i * 8] = *(const half8*)&frags[i * 8];
    if (tid < 384)
        *(half8*)&wo_lds[tid * 8] = *(const half8*)&frags[REGW_OFF + tid * 8];
    for (int i = tid; i < ROWS * HID / 4; i += 768) {
        float4 v = *(const float4*)&h0[(size_t)base * HID + i * 4];
        int row = (i * 4) / HID, k = (i * 4) - row * HID;
        hbuf[0][row][k]     = (_Float16)v.x;
        hbuf[0][row][k + 1] = (_Float16)v.y;
        hbuf[0][row][k + 2] = (_Float16)v.z;
        hbuf[0][row][k + 3] = (_Float16)v.w;
    }
    if (tid < T_STEPS * ROWS) {      // x for all steps, once
        int t = tid >> 5, r = tid & 31;
        int src = (t == 0) ? 0 : (t - 1);
        x_all[t][r] = *(const float2*)&obs[((size_t)src * NSEQ + base + r) * 2];
    }

    const float bo_n = (l16 < 2) ? b_out[l16] : 0.f;

    float c[8];
#pragma unroll
    for (int i = 0; i < 8; ++i) c[i] = 0.f;

    const int j = ht * 16 + l16;
    float bs[4], w0[4], w1[4];
#pragma unroll
    for (int g = 0; g < 4; ++g) {
        bs[g] = b_ih[g * HID + j] + b_hh[g * HID + j];
        w0[g] = w_ih[(g * HID + j) * 2];
        w1[g] = w_ih[(g * HID + j) * 2 + 1];
    }

    // ---- initial cross-barrier prefetch: kc2,kc3 (8 frags, 32 VGPRs) ----
    half8 bpre[8];
    {
        const _Float16* pp = frags + REGA_SZ + ht * 8192 + lane * 8;
        asm volatile("" : "+v"(pp));
#pragma unroll
        for (int q = 0; q < 8; ++q)
            bpre[q] = *(const half8*)(pp + q * 512);
    }

    __syncthreads();

    for (int t = 0; t < T_STEPS; ++t) {
        const _Float16* hb = &hbuf[t & 1][0][0];
        _Float16*       hn = &hbuf[(t + 1) & 1][0][0];

        // ---- step-top stream: kc4,kc5 (8 frags, 32 VGPRs; ~250 cyc of
        // kc0-3 work before first use). Opaque ptr defeats LICM.
        const _Float16* ps = frags + REGA_SZ + ht * 8192 + 4096 + lane * 8;
        asm volatile("" : "+v"(ps));
        half8 bst2[8];
#pragma unroll
        for (int q = 0; q < 8; ++q)
            bst2[q] = *(const half8*)(ps + q * 512);

        // ================= gate MFMA phase (reads hbuf[t&1]) =================
        floatx4 acc[2][4];
#pragma unroll
        for (int rt = 0; rt < 2; ++rt)
#pragma unroll
            for (int g = 0; g < 4; ++g)
                acc[rt][g] = (floatx4){0.f, 0.f, 0.f, 0.f};

        // kc 0..1 from LDS
#pragma unroll
        for (int kc = 0; kc < 2; ++kc) {
            half8 bt[4];
#pragma unroll
            for (int g = 0; g < 4; ++g)
                bt[g] = *(const half8*)&b_lds[((ht * 2 + kc) * 4 + g) * 512 + lane * 8];
#pragma unroll
            for (int rt = 0; rt < 2; ++rt) {
                half8 a = *(const half8*)(hb + (rt * 16 + l16) * HPAD + kc * 32 + quad * 8);
#pragma unroll
                for (int g = 0; g < 4; ++g)
                    acc[rt][g] = __builtin_amdgcn_mfma_f32_16x16x32_f16(a, bt[g], acc[rt][g], 0, 0, 0);
            }
        }
        // kc 2..3 from the cross-barrier prefetch (long in flight -> no stall)
#pragma unroll
        for (int kc2 = 0; kc2 < 2; ++kc2) {
#pragma unroll
            for (int rt = 0; rt < 2; ++rt) {
                half8 a = *(const half8*)(hb + (rt * 16 + l16) * HPAD + (kc2 + 2) * 32 + quad * 8);
#pragma unroll
                for (int g = 0; g < 4; ++g)
                    acc[rt][g] = __builtin_amdgcn_mfma_f32_16x16x32_f16(a, bpre[kc2 * 4 + g], acc[rt][g], 0, 0, 0);
            }
        }
        // kc 4..5 from the step-top stream
#pragma unroll
        for (int kc2 = 0; kc2 < 2; ++kc2) {
#pragma unroll
            for (int rt = 0; rt < 2; ++rt) {
                half8 a = *(const half8*)(hb + (rt * 16 + l16) * HPAD + (kc2 + 4) * 32 + quad * 8);
#pragma unroll
                for (int g = 0; g < 4; ++g)
                    acc[rt][g] = __builtin_amdgcn_mfma_f32_16x16x32_f16(a, bst2[kc2 * 4 + g], acc[rt][g], 0, 0, 0);
            }
        }

        // ---- out_{t-1} = h_t @ w_out.T + b_out (wave 0, also reads hbuf[t&1]) ----
        if (ht == 0 && t > 0) {
            const int ot = t - 1;
#pragma unroll
            for (int rt = 0; rt < 2; ++rt) {
                floatx4 ao = {bo_n, bo_n, bo_n, bo_n};
#pragma unroll
                for (int kc = 0; kc < 6; ++kc) {
                    half8 a = *(const half8*)(hb + (rt * 16 + l16) * HPAD + kc * 32 + quad * 8);
                    half8 b = *(const half8*)&wo_lds[kc * 512 + lane * 8];
                    ao = __builtin_amdgcn_mfma_f32_16x16x32_f16(a, b, ao, 0, 0, 0);
                }
                if (l16 < 2) {
#pragma unroll
                    for (int r = 0; r < 4; ++r)
                        out[((size_t)ot * NSEQ + base + rt * 16 + quad * 4 + r) * 2 + l16] = ao[r];
                }
            }
        }

        // ============ activation phase (writes hbuf[(t+1)&1]) ============
#pragma unroll
        for (int rt = 0; rt < 2; ++rt) {
#pragma unroll
            for (int r = 0; r < 4; ++r) {
                const int row = rt * 16 + quad * 4 + r;
                const float2 xv = x_all[t][row];
                const float gi = acc[rt][0][r] + bs[0] + xv.x * w0[0] + xv.y * w1[0];
                const float gf = acc[rt][1][r] + bs[1] + xv.x * w0[1] + xv.y * w1[1];
                const float gg = acc[rt][2][r] + bs[2] + xv.x * w0[2] + xv.y * w1[2];
                const float go = acc[rt][3][r] + bs[3] + xv.x * w0[3] + xv.y * w1[3];
                const int ci = rt * 4 + r;
                const float cn = fsig(gf) * c[ci] + fsig(gi) * ftanh(gg);
                c[ci] = cn;
                hn[row * HPAD + j] = (_Float16)(fsig(go) * ftanh(cn));
            }
        }

        // ---- cross-barrier prefetch for step t+1: kc2,kc3 ----
        {
            const _Float16* pp = frags + REGA_SZ + ht * 8192 + lane * 8;
            asm volatile("" : "+v"(pp));
#pragma unroll
            for (int q = 0; q < 8; ++q)
                bpre[q] = *(const half8*)(pp + q * 512);
        }

        __syncthreads();   // h_{t+1} done; bpre stays in flight across this
    }

    // ---- out_19 from h_20 (in hbuf[0]) ----
    if (ht == 0) {
        const _Float16* hb = &hbuf[0][0][0];
#pragma unroll
        for (int rt = 0; rt < 2; ++rt) {
            floatx4 ao = {bo_n, bo_n, bo_n, bo_n};
#pragma unroll
            for (int kc = 0; kc < 6; ++kc) {
                half8 a = *(const half8*)(hb + (rt * 16 + l16) * HPAD + kc * 32 + quad * 8);
                half8 b = *(const half8*)&wo_lds[kc * 512 + lane * 8];
                ao = __builtin_amdgcn_mfma_f32_16x16x32_f16(a, b, ao, 0, 0, 0);
            }
            if (l16 < 2) {
#pragma unroll
                for (int r = 0; r < 4; ++r)
                    out[((size_t)19 * NSEQ + base + rt * 16 + quad * 4 + r) * 2 + l16] = ao[r];
            }
        }
    }
}

extern "C" void kernel_launch(void* const* d_in, const int* in_sizes, int n_in,
                              void* d_out, int out_size, void* d_ws, size_t ws_size,
                              hipStream_t stream) {
    const float* obs  = (const float*)d_in[0];
    const float* h0   = (const float*)d_in[1];
    const float* wih  = (const float*)d_in[2];
    const float* whh  = (const float*)d_in[3];
    const float* bih  = (const float*)d_in[4];
    const float* bhh  = (const float*)d_in[5];
    const float* wout = (const float*)d_in[6];
    const float* bout = (const float*)d_in[7];
    float* out = (float*)d_out;
    _Float16* frags = (_Float16*)d_ws;   // 301056 B used

    build_frags<<<(REGW_OFF + 3072 + 255) / 256, 256, 0, stream>>>(whh, wout, frags);
    lstm_fused_kernel<<<NSEQ / ROWS, 768, 0, stream>>>(
        obs, h0, wih, bih, bhh, bout, frags, out);
}